// Round 15
// baseline (229.205 us; speedup 1.0000x reference)
//
#include <hip/hip_runtime.h>
#include <hip/hip_bf16.h>

#define T_N 500000
#define NTILE 31250          // T_N / 16 rows per wave-tile (exact)
#define NBLKC 1024           // critic blocks (4 waves each)
#define NBLKA 1024           // actor blocks
#define NCHUNK 4096
#define CHUNKL 128
#define NPART 1024

typedef __attribute__((ext_vector_type(8))) short short8v;
typedef __attribute__((ext_vector_type(4))) float float4v;
typedef __attribute__((ext_vector_type(4))) float f4v;

__device__ __forceinline__ short f2bf(float f) {
    __hip_bfloat16 b = __float2bfloat16(f);
    return *reinterpret_cast<short*>(&b);
}
__device__ __forceinline__ float bf2f(short s) {
    return __uint_as_float(((unsigned)(unsigned short)s) << 16);
}

__device__ __forceinline__ short8v cvt8v(f4v a, f4v b) {
    short8v r;
    r[0] = f2bf(a[0]); r[1] = f2bf(a[1]); r[2] = f2bf(a[2]); r[3] = f2bf(a[3]);
    r[4] = f2bf(b[0]); r[5] = f2bf(b[1]); r[6] = f2bf(b[2]); r[7] = f2bf(b[3]);
    return r;
}
// non-temporal x load: streaming data stays out of L1 so weights remain resident
__device__ __forceinline__ f4v ldnt(const float* p) {
    return __builtin_nontemporal_load(reinterpret_cast<const f4v*>(p));
}

// W^T A-fragments (each = 64 lanes x 8 bf16 = 1KB)
#define FC1 0    // critic W1^T: 4 k-steps x 4 out-tiles
#define FA1 16   // actor  W1^T
#define FC2 32   // critic W2^T: 2 k-steps x 4 out-tiles
#define FA2 40   // actor  W2^T
#define FA3 48   // actor  W3^T: 2 k-steps (16 actions)
#define NFRAG 50

// output-feature permutation: C-row r of out-tile c holds feature feat(c,r),
// chosen so a lane's C-fragment IS the next layer's B-fragment.
__device__ __forceinline__ int featperm(int c, int r) {
    return ((c >> 1) << 5) + ((r >> 2) << 3) + ((c & 1) << 2) + (r & 3);
}

__global__ __launch_bounds__(64) void k_pack(
    const float* __restrict__ cW1, const float* __restrict__ aW1,
    const float* __restrict__ cW2, const float* __restrict__ aW2,
    const float* __restrict__ aW3, short8v* __restrict__ packed)
{
    const int f = blockIdx.x, l = threadIdx.x;
    const int g = l >> 4, r = l & 15;
    const float* W; int s, c, ncol; bool perm = true;
    if (f < FA1)      { W = cW1; s = f >> 2;         c = f & 3;         ncol = 64; }
    else if (f < FC2) { W = aW1; s = (f - FA1) >> 2; c = (f - FA1) & 3; ncol = 64; }
    else if (f < FA2) { W = cW2; s = (f - FC2) >> 2; c = (f - FC2) & 3; ncol = 64; }
    else if (f < FA3) { W = aW2; s = (f - FA2) >> 2; c = (f - FA2) & 3; ncol = 64; }
    else              { W = aW3; s = f - FA3;        c = 0;             ncol = 16; perm = false; }
    const int col = perm ? featperm(c, r) : r;
    short8v frag;
    #pragma unroll
    for (int j = 0; j < 8; ++j) {
        int k = s * 32 + g * 8 + j;        // W row = contraction index
        frag[j] = f2bf(W[k * ncol + col]);
    }
    packed[f * 64 + l] = frag;
}

// next layer's B-frag from accs: slot j of frag s = relu(acc[2s+(j>>2)][j&3])
__device__ __forceinline__ void mk_bfrag(const float4v* acc, short8v* bf) {
    #pragma unroll
    for (int s = 0; s < 2; ++s)
        #pragma unroll
        for (int j = 0; j < 8; ++j)
            bf[s][j] = f2bf(fmaxf(acc[2 * s + (j >> 2)][j & 3], 0.f));
}

// ======== k_critic: critic-only, 26KB weight set (L1-resident) ========
__global__ __launch_bounds__(256) void k_critic(
    const float* __restrict__ states, const float* __restrict__ next_states,
    const short8v* __restrict__ pk,
    const float* __restrict__ cb1, const float* __restrict__ cb2,
    const float* __restrict__ cW3, const float* __restrict__ cb3,
    float* __restrict__ v_o, float* __restrict__ nv_o)
{
    const int l = threadIdx.x & 63;
    const int g = l >> 4, q = l & 15;
    const int wid = blockIdx.x * 4 + (threadIdx.x >> 6);
    const int NW = NBLKC * 4;
    const float cb3v = cb3[0];
    int off[4];
    #pragma unroll
    for (int c = 0; c < 4; ++c) off[c] = ((c >> 1) << 5) + (g << 3) + ((c & 1) << 2);

    // prologue: tile 0 raws (nt loads)
    f4v ra[8], rb[8];
    {
        const float* xs = states + ((long long)wid * 16 + q) * 128 + g * 8;
        const float* xn = next_states + ((long long)wid * 16 + q) * 128 + g * 8;
        #pragma unroll
        for (int s = 0; s < 4; ++s) {
            ra[2 * s]     = ldnt(xs + s * 32);
            ra[2 * s + 1] = ldnt(xs + s * 32 + 4);
            rb[2 * s]     = ldnt(xn + s * 32);
            rb[2 * s + 1] = ldnt(xn + s * 32 + 4);
        }
    }

    for (long long t = wid; t < NTILE; t += NW) {
        const long long r0 = t * 16;
        const bool more = (t + NW) < NTILE;

        // ---- states pass ----
        short8v sa[4];
        #pragma unroll
        for (int s = 0; s < 4; ++s) sa[s] = cvt8v(ra[2 * s], ra[2 * s + 1]);
        if (more) {
            const float* xs = states + ((t + NW) * 16 + q) * 128 + g * 8;
            #pragma unroll
            for (int s = 0; s < 4; ++s) {
                ra[2 * s]     = ldnt(xs + s * 32);
                ra[2 * s + 1] = ldnt(xs + s * 32 + 4);
            }
        }
        float4v acc[4];
        short8v bf[2];
        #pragma unroll
        for (int c = 0; c < 4; ++c) {
            float4 b = *reinterpret_cast<const float4*>(cb1 + off[c]);
            acc[c] = (float4v){b.x, b.y, b.z, b.w};
        }
        #pragma unroll
        for (int s = 0; s < 4; ++s)
            #pragma unroll
            for (int c = 0; c < 4; ++c)
                acc[c] = __builtin_amdgcn_mfma_f32_16x16x32_bf16(
                    pk[(FC1 + s * 4 + c) * 64 + l], sa[s], acc[c], 0, 0, 0);
        mk_bfrag(acc, bf);
        #pragma unroll
        for (int c = 0; c < 4; ++c) {
            float4 b = *reinterpret_cast<const float4*>(cb2 + off[c]);
            acc[c] = (float4v){b.x, b.y, b.z, b.w};
        }
        #pragma unroll
        for (int s = 0; s < 2; ++s)
            #pragma unroll
            for (int c = 0; c < 4; ++c)
                acc[c] = __builtin_amdgcn_mfma_f32_16x16x32_bf16(
                    pk[(FC2 + s * 4 + c) * 64 + l], bf[s], acc[c], 0, 0, 0);
        {
            float vp = 0.f;
            #pragma unroll
            for (int c = 0; c < 4; ++c) {
                float4 w3v = *reinterpret_cast<const float4*>(cW3 + off[c]);
                const float w4[4] = {w3v.x, w3v.y, w3v.z, w3v.w};
                #pragma unroll
                for (int u = 0; u < 4; ++u)
                    vp = fmaf(fmaxf(acc[c][u], 0.f), w4[u], vp);
            }
            vp += __shfl_xor(vp, 16); vp += __shfl_xor(vp, 32);
            if (g == 0) v_o[r0 + q] = vp + cb3v;
        }

        // ---- next_states pass ----
        short8v na[4];
        #pragma unroll
        for (int s = 0; s < 4; ++s) na[s] = cvt8v(rb[2 * s], rb[2 * s + 1]);
        if (more) {
            const float* xn = next_states + ((t + NW) * 16 + q) * 128 + g * 8;
            #pragma unroll
            for (int s = 0; s < 4; ++s) {
                rb[2 * s]     = ldnt(xn + s * 32);
                rb[2 * s + 1] = ldnt(xn + s * 32 + 4);
            }
        }
        #pragma unroll
        for (int c = 0; c < 4; ++c) {
            float4 b = *reinterpret_cast<const float4*>(cb1 + off[c]);
            acc[c] = (float4v){b.x, b.y, b.z, b.w};
        }
        #pragma unroll
        for (int s = 0; s < 4; ++s)
            #pragma unroll
            for (int c = 0; c < 4; ++c)
                acc[c] = __builtin_amdgcn_mfma_f32_16x16x32_bf16(
                    pk[(FC1 + s * 4 + c) * 64 + l], na[s], acc[c], 0, 0, 0);
        mk_bfrag(acc, bf);
        #pragma unroll
        for (int c = 0; c < 4; ++c) {
            float4 b = *reinterpret_cast<const float4*>(cb2 + off[c]);
            acc[c] = (float4v){b.x, b.y, b.z, b.w};
        }
        #pragma unroll
        for (int s = 0; s < 2; ++s)
            #pragma unroll
            for (int c = 0; c < 4; ++c)
                acc[c] = __builtin_amdgcn_mfma_f32_16x16x32_bf16(
                    pk[(FC2 + s * 4 + c) * 64 + l], bf[s], acc[c], 0, 0, 0);
        {
            float np = 0.f;
            #pragma unroll
            for (int c = 0; c < 4; ++c) {
                float4 w3v = *reinterpret_cast<const float4*>(cW3 + off[c]);
                const float w4[4] = {w3v.x, w3v.y, w3v.z, w3v.w};
                #pragma unroll
                for (int u = 0; u < 4; ++u)
                    np = fmaf(fmaxf(acc[c][u], 0.f), w4[u], np);
            }
            np += __shfl_xor(np, 16); np += __shfl_xor(np, 32);
            if (g == 0) nv_o[r0 + q] = np + cb3v;
        }
    }
}

// ======== k_actor_mlp: actor-only, 26.6KB weight set (L1-resident) ========
__global__ __launch_bounds__(256) void k_actor_mlp(
    const float* __restrict__ states, const short8v* __restrict__ pk,
    const float* __restrict__ ab1, const float* __restrict__ ab2,
    const float* __restrict__ ab3, short* __restrict__ logit_o)
{
    const int l = threadIdx.x & 63;
    const int g = l >> 4, q = l & 15;
    const int wid = blockIdx.x * 4 + (threadIdx.x >> 6);
    const int NW = NBLKA * 4;
    int off[4];
    #pragma unroll
    for (int c = 0; c < 4; ++c) off[c] = ((c >> 1) << 5) + (g << 3) + ((c & 1) << 2);

    f4v ra[8];
    {
        const float* xs = states + ((long long)wid * 16 + q) * 128 + g * 8;
        #pragma unroll
        for (int s = 0; s < 4; ++s) {
            ra[2 * s]     = ldnt(xs + s * 32);
            ra[2 * s + 1] = ldnt(xs + s * 32 + 4);
        }
    }

    for (long long t = wid; t < NTILE; t += NW) {
        const long long r0 = t * 16;
        const bool more = (t + NW) < NTILE;

        short8v sa[4];
        #pragma unroll
        for (int s = 0; s < 4; ++s) sa[s] = cvt8v(ra[2 * s], ra[2 * s + 1]);
        if (more) {
            const float* xs = states + ((t + NW) * 16 + q) * 128 + g * 8;
            #pragma unroll
            for (int s = 0; s < 4; ++s) {
                ra[2 * s]     = ldnt(xs + s * 32);
                ra[2 * s + 1] = ldnt(xs + s * 32 + 4);
            }
        }

        float4v acc[4];
        short8v bf[2];
        // actor L1
        #pragma unroll
        for (int c = 0; c < 4; ++c) {
            float4 b = *reinterpret_cast<const float4*>(ab1 + off[c]);
            acc[c] = (float4v){b.x, b.y, b.z, b.w};
        }
        #pragma unroll
        for (int s = 0; s < 4; ++s)
            #pragma unroll
            for (int c = 0; c < 4; ++c)
                acc[c] = __builtin_amdgcn_mfma_f32_16x16x32_bf16(
                    pk[(FA1 + s * 4 + c) * 64 + l], sa[s], acc[c], 0, 0, 0);
        mk_bfrag(acc, bf);
        // actor L2
        #pragma unroll
        for (int c = 0; c < 4; ++c) {
            float4 b = *reinterpret_cast<const float4*>(ab2 + off[c]);
            acc[c] = (float4v){b.x, b.y, b.z, b.w};
        }
        #pragma unroll
        for (int s = 0; s < 2; ++s)
            #pragma unroll
            for (int c = 0; c < 4; ++c)
                acc[c] = __builtin_amdgcn_mfma_f32_16x16x32_bf16(
                    pk[(FA2 + s * 4 + c) * 64 + l], bf[s], acc[c], 0, 0, 0);
        mk_bfrag(acc, bf);
        // actor L3 + logit store
        {
            float4 b3 = *reinterpret_cast<const float4*>(ab3 + g * 4);
            float4v a3 = (float4v){b3.x, b3.y, b3.z, b3.w};
            #pragma unroll
            for (int s = 0; s < 2; ++s)
                a3 = __builtin_amdgcn_mfma_f32_16x16x32_bf16(
                    pk[(FA3 + s) * 64 + l], bf[s], a3, 0, 0, 0);
            unsigned w0 = ((unsigned)(unsigned short)f2bf(a3[1]) << 16) |
                          (unsigned)(unsigned short)f2bf(a3[0]);
            unsigned w1 = ((unsigned)(unsigned short)f2bf(a3[3]) << 16) |
                          (unsigned)(unsigned short)f2bf(a3[2]);
            uint2 lw; lw.x = w0; lw.y = w1;
            *reinterpret_cast<uint2*>(logit_o + (r0 + q) * 16 + g * 4) = lw;
        }
    }
}

// ---------------- GAE chunk: delta/coef on the fly ----------------
__device__ __forceinline__ void dc_elem(float v, float nv, float rw, float dn,
                                        float& d, float& c) {
    float nd = 1.f - dn;
    d = fmaf(0.99f * nd, nv, rw) - v;
    c = (0.99f * 0.95f) * nd;
}

__global__ __launch_bounds__(256) void k_gae_chunk(
    const float* __restrict__ v_i, const float* __restrict__ nv_i,
    const float* __restrict__ rewards, const float* __restrict__ dones,
    float* __restrict__ P, float* __restrict__ Q)
{
    const int c = blockIdx.x * 256 + threadIdx.x;
    const long long lo = (long long)c * CHUNKL;
    float p = 1.f, a = 0.f;
    if (lo < T_N) {
        const int n = (int)((T_N - lo < CHUNKL) ? (T_N - lo) : CHUNKL);
        for (int j = (n >> 2) - 1; j >= 0; --j) {
            float4 vv = *reinterpret_cast<const float4*>(&v_i[lo + 4 * j]);
            float4 nn = *reinterpret_cast<const float4*>(&nv_i[lo + 4 * j]);
            float4 rw = *reinterpret_cast<const float4*>(&rewards[lo + 4 * j]);
            float4 dn = *reinterpret_cast<const float4*>(&dones[lo + 4 * j]);
            float d0, c0, d1, c1, d2, c2, d3, c3;
            dc_elem(vv.x, nn.x, rw.x, dn.x, d0, c0);
            dc_elem(vv.y, nn.y, rw.y, dn.y, d1, c1);
            dc_elem(vv.z, nn.z, rw.z, dn.z, d2, c2);
            dc_elem(vv.w, nn.w, rw.w, dn.w, d3, c3);
            a = fmaf(c3, a, d3);
            a = fmaf(c2, a, d2);
            a = fmaf(c1, a, d1);
            a = fmaf(c0, a, d0);
            p *= c0 * c1 * c2 * c3;
        }
    }
    P[c] = p; Q[c] = a;
}

__global__ __launch_bounds__(1024) void k_gae_scan(
    const float* __restrict__ P, const float* __restrict__ Q,
    float* __restrict__ carry)
{
    __shared__ float sp[1024], sq[1024];
    const int t = threadIdx.x, b = t * 4;
    float p = P[b + 3], q = Q[b + 3];
    #pragma unroll
    for (int c = 2; c >= 0; --c) {
        float pc = P[b + c], qc = Q[b + c];
        q = fmaf(pc, q, qc);
        p = pc * p;
    }
    sp[t] = p; sq[t] = q;
    __syncthreads();
    for (int d = 1; d < 1024; d <<= 1) {
        float pp = sp[t], qq = sq[t];
        float p2 = 1.f, q2 = 0.f;
        const bool has = (t + d) < 1024;
        if (has) { p2 = sp[t + d]; q2 = sq[t + d]; }
        __syncthreads();
        if (has) { sp[t] = pp * p2; sq[t] = fmaf(pp, q2, qq); }
        __syncthreads();
    }
    float x = (t + 1 < 1024) ? sq[t + 1] : 0.f;
    #pragma unroll
    for (int c = 3; c >= 0; --c) {
        carry[b + c] = x;
        x = fmaf(P[b + c], x, Q[b + c]);
    }
}

__global__ __launch_bounds__(256) void k_gae_apply(
    const float* __restrict__ v_i, const float* __restrict__ nv_i,
    const float* __restrict__ rewards, const float* __restrict__ dones,
    const float* __restrict__ carry, float* __restrict__ adv,
    float* __restrict__ part)
{
    const int c = blockIdx.x * 256 + threadIdx.x;
    const long long lo = (long long)c * CHUNKL;
    float s = 0.f, s2 = 0.f;
    if (lo < T_N) {
        const int n = (int)((T_N - lo < CHUNKL) ? (T_N - lo) : CHUNKL);
        float a = carry[c];
        for (int j = (n >> 2) - 1; j >= 0; --j) {
            float4 vv = *reinterpret_cast<const float4*>(&v_i[lo + 4 * j]);
            float4 nn = *reinterpret_cast<const float4*>(&nv_i[lo + 4 * j]);
            float4 rw = *reinterpret_cast<const float4*>(&rewards[lo + 4 * j]);
            float4 dn = *reinterpret_cast<const float4*>(&dones[lo + 4 * j]);
            float d0, c0, d1, c1, d2, c2, d3, c3;
            dc_elem(vv.x, nn.x, rw.x, dn.x, d0, c0);
            dc_elem(vv.y, nn.y, rw.y, dn.y, d1, c1);
            dc_elem(vv.z, nn.z, rw.z, dn.z, d2, c2);
            dc_elem(vv.w, nn.w, rw.w, dn.w, d3, c3);
            float a3 = fmaf(c3, a, d3);
            float a2v = fmaf(c2, a3, d2);
            float a1 = fmaf(c1, a2v, d1);
            float a0 = fmaf(c0, a1, d0);
            float4 o; o.x = a0; o.y = a1; o.z = a2v; o.w = a3;
            *reinterpret_cast<float4*>(&adv[lo + 4 * j]) = o;
            a = a0;
            s += a0 + a1 + a2v + a3;
            s2 += a0 * a0 + a1 * a1 + a2v * a2v + a3 * a3;
        }
    }
    #pragma unroll
    for (int o = 32; o > 0; o >>= 1) { s += __shfl_down(s, o); s2 += __shfl_down(s2, o); }
    __shared__ float l0[4], l1[4];
    const int wv = threadIdx.x >> 6, ln = threadIdx.x & 63;
    if (ln == 0) { l0[wv] = s; l1[wv] = s2; }
    __syncthreads();
    if (threadIdx.x == 0) {
        part[blockIdx.x * 2]     = l0[0] + l0[1] + l0[2] + l0[3];
        part[blockIdx.x * 2 + 1] = l1[0] + l1[1] + l1[2] + l1[3];
    }
}

__global__ __launch_bounds__(256) void k_actor(
    const float* __restrict__ adv, const short* __restrict__ logits,
    const float* __restrict__ old_logp, const int* __restrict__ actions,
    const float* __restrict__ part, float* __restrict__ part4)
{
    __shared__ float st[2];
    if (threadIdx.x == 0) {
        float S = 0.f, S2 = 0.f;
        #pragma unroll
        for (int i = 0; i < 16; ++i) { S += part[2 * i]; S2 += part[2 * i + 1]; }
        const float Tf = (float)T_N;
        float mean = S / Tf;
        float var = (S2 - S * S / Tf) / (Tf - 1.f);
        st[0] = mean;
        st[1] = 1.f / (sqrtf(fmaxf(var, 0.f)) + 1e-8f);
    }
    __syncthreads();
    const float mean = st[0], isd = st[1];
    float sm = 0.f, sent = 0.f;
    for (long long i = (long long)blockIdx.x * 256 + threadIdx.x; i < T_N;
         i += (long long)gridDim.x * 256) {
        const short8v* lp = reinterpret_cast<const short8v*>(logits) + i * 2;
        short8v lo0 = lp[0], lo1 = lp[1];
        float lg[16];
        #pragma unroll
        for (int j = 0; j < 8; ++j) { lg[j] = bf2f(lo0[j]); lg[8 + j] = bf2f(lo1[j]); }
        float m = lg[0];
        #pragma unroll
        for (int a = 1; a < 16; ++a) m = fmaxf(m, lg[a]);
        float se = 0.f, tt = 0.f;
        #pragma unroll
        for (int a = 0; a < 16; ++a) {
            float e = __expf(lg[a] - m);
            se += e;
            tt = fmaf(e, lg[a], tt);
        }
        float ls = __logf(se);
        float ent = m + ls - tt / se;
        const int act = actions[i];
        float lsel = lg[0];
        #pragma unroll
        for (int a = 1; a < 16; ++a) lsel = (a == act) ? lg[a] : lsel;
        float logp = lsel - m - ls;
        float rt = __expf(logp - old_logp[i]);
        float an = (adv[i] - mean) * isd;
        sm += fminf(rt * an, fminf(fmaxf(rt, 0.8f), 1.2f) * an);
        sent += ent;
    }
    #pragma unroll
    for (int o = 32; o > 0; o >>= 1) { sm += __shfl_down(sm, o); sent += __shfl_down(sent, o); }
    __shared__ float l0[4], l1[4];
    const int wv = threadIdx.x >> 6, ln = threadIdx.x & 63;
    if (ln == 0) { l0[wv] = sm; l1[wv] = sent; }
    __syncthreads();
    if (threadIdx.x == 0) {
        part4[blockIdx.x * 2]     = l0[0] + l0[1] + l0[2] + l0[3];
        part4[blockIdx.x * 2 + 1] = l1[0] + l1[1] + l1[2] + l1[3];
    }
}

__global__ __launch_bounds__(1024) void k_final(
    const float* __restrict__ part4, const float* __restrict__ part,
    float* __restrict__ out)
{
    const int t = threadIdx.x;
    float sm = part4[t * 2], se = part4[t * 2 + 1];
    #pragma unroll
    for (int o = 32; o > 0; o >>= 1) { sm += __shfl_down(sm, o); se += __shfl_down(se, o); }
    __shared__ float l0[16], l1[16];
    const int wv = t >> 6, ln = t & 63;
    if (ln == 0) { l0[wv] = sm; l1[wv] = se; }
    __syncthreads();
    if (t == 0) {
        float SM = 0.f, SE = 0.f;
        #pragma unroll
        for (int i = 0; i < 16; ++i) { SM += l0[i]; SE += l1[i]; }
        float S2 = 0.f;
        #pragma unroll
        for (int i = 0; i < 16; ++i) S2 += part[2 * i + 1];
        const float Tf = (float)T_N;
        float actor_loss = -SM / Tf;
        float ent_loss = SE / Tf;
        float critic_loss = S2 / Tf;
        float total = actor_loss + 0.5f * critic_loss - 0.01f * ent_loss;
        out[0] = total; out[1] = actor_loss; out[2] = critic_loss; out[3] = ent_loss;
    }
}

extern "C" void kernel_launch(void* const* d_in, const int* in_sizes, int n_in,
                              void* d_out, int out_size, void* d_ws, size_t ws_size,
                              hipStream_t stream) {
    (void)in_sizes; (void)n_in; (void)out_size; (void)ws_size;
    const float* states      = (const float*)d_in[0];
    const float* next_states = (const float*)d_in[1];
    const float* rewards     = (const float*)d_in[2];
    const float* dones       = (const float*)d_in[3];
    const int*   actions     = (const int*)d_in[4];
    const float* old_logp    = (const float*)d_in[5];
    const float* aW1 = (const float*)d_in[6];  const float* ab1 = (const float*)d_in[7];
    const float* aW2 = (const float*)d_in[8];  const float* ab2 = (const float*)d_in[9];
    const float* aW3 = (const float*)d_in[10]; const float* ab3 = (const float*)d_in[11];
    const float* cW1 = (const float*)d_in[12]; const float* cb1 = (const float*)d_in[13];
    const float* cW2 = (const float*)d_in[14]; const float* cb2 = (const float*)d_in[15];
    const float* cW3 = (const float*)d_in[16]; const float* cb3 = (const float*)d_in[17];
    float* out = (float*)d_out;

    short* logits = (short*)d_ws;                           // 16 MB
    float* fbase = (float*)(logits + (size_t)T_N * 16);
    float* v_ws  = fbase;
    float* nv_ws = fbase + (size_t)T_N;
    float* adv   = fbase + 2 * (size_t)T_N;
    float* P     = fbase + 3 * (size_t)T_N;
    float* Q     = P + NCHUNK;
    float* carry = Q + NCHUNK;
    float* part  = carry + NCHUNK;
    float* part4 = part + 32;
    short8v* packed = (short8v*)(part4 + 2048);

    k_pack<<<NFRAG, 64, 0, stream>>>(cW1, aW1, cW2, aW2, aW3, packed);
    k_critic<<<NBLKC, 256, 0, stream>>>(
        states, next_states, packed, cb1, cb2, cW3, cb3, v_ws, nv_ws);
    k_actor_mlp<<<NBLKA, 256, 0, stream>>>(
        states, packed, ab1, ab2, ab3, logits);
    k_gae_chunk<<<NCHUNK / 256, 256, 0, stream>>>(v_ws, nv_ws, rewards, dones, P, Q);
    k_gae_scan<<<1, 1024, 0, stream>>>(P, Q, carry);
    k_gae_apply<<<NCHUNK / 256, 256, 0, stream>>>(v_ws, nv_ws, rewards, dones, carry, adv, part);
    k_actor<<<NPART, 256, 0, stream>>>(adv, logits, old_logp, actions, part, part4);
    k_final<<<1, 1024, 0, stream>>>(part4, part, out);
}

// Round 16
// 192.865 us; speedup vs baseline: 1.1884x; 1.1884x over previous
//
#include <hip/hip_runtime.h>
#include <hip/hip_bf16.h>

#define T_N 500000
#define NTILE 31250          // T_N / 16 rows per wave-tile (exact)
#define NBLK 512             // 2 blocks/CU, 2 waves/SIMD resident
#define NWAVES (NBLK * 4)    // 2048 persistent waves
#define NCHUNK 4096
#define CHUNKL 128
#define NPART 1024

typedef __attribute__((ext_vector_type(8))) short short8v;
typedef __attribute__((ext_vector_type(4))) float float4v;

__device__ __forceinline__ short f2bf(float f) {
    __hip_bfloat16 b = __float2bfloat16(f);
    return *reinterpret_cast<short*>(&b);
}
__device__ __forceinline__ float bf2f(short s) {
    return __uint_as_float(((unsigned)(unsigned short)s) << 16);
}

__device__ __forceinline__ short8v cvt8(const float4 a, const float4 b) {
    short8v r;
    r[0] = f2bf(a.x); r[1] = f2bf(a.y); r[2] = f2bf(a.z); r[3] = f2bf(a.w);
    r[4] = f2bf(b.x); r[5] = f2bf(b.y); r[6] = f2bf(b.z); r[7] = f2bf(b.w);
    return r;
}

// W^T A-fragments (each = 64 lanes x 8 bf16 = 1KB)
#define FC1 0    // critic W1^T: 4 k-steps x 4 out-tiles
#define FA1 16   // actor  W1^T
#define FC2 32   // critic W2^T: 2 k-steps x 4 out-tiles
#define FA2 40   // actor  W2^T
#define FA3 48   // actor  W3^T: 2 k-steps (16 actions)
#define NFRAG 50

// output-feature permutation: C-row r of out-tile c holds feature feat(c,r),
// chosen so a lane's C-fragment IS the next layer's B-fragment.
__device__ __forceinline__ int featperm(int c, int r) {
    return ((c >> 1) << 5) + ((r >> 2) << 3) + ((c & 1) << 2) + (r & 3);
}

__global__ __launch_bounds__(64) void k_pack(
    const float* __restrict__ cW1, const float* __restrict__ aW1,
    const float* __restrict__ cW2, const float* __restrict__ aW2,
    const float* __restrict__ aW3, short8v* __restrict__ packed)
{
    const int f = blockIdx.x, l = threadIdx.x;
    const int g = l >> 4, r = l & 15;
    const float* W; int s, c, ncol; bool perm = true;
    if (f < FA1)      { W = cW1; s = f >> 2;         c = f & 3;         ncol = 64; }
    else if (f < FC2) { W = aW1; s = (f - FA1) >> 2; c = (f - FA1) & 3; ncol = 64; }
    else if (f < FA2) { W = cW2; s = (f - FC2) >> 2; c = (f - FC2) & 3; ncol = 64; }
    else if (f < FA3) { W = aW2; s = (f - FA2) >> 2; c = (f - FA2) & 3; ncol = 64; }
    else              { W = aW3; s = f - FA3;        c = 0;             ncol = 16; perm = false; }
    const int col = perm ? featperm(c, r) : r;
    short8v frag;
    #pragma unroll
    for (int j = 0; j < 8; ++j) {
        int k = s * 32 + g * 8 + j;        // W row = contraction index
        frag[j] = f2bf(W[k * ncol + col]);
    }
    packed[f * 64 + l] = frag;
}

// next layer's B-frag from accs: slot j of frag s = relu(acc[2s+(j>>2)][j&3])
__device__ __forceinline__ void mk_bfrag(const float4v* acc, short8v* bf) {
    #pragma unroll
    for (int s = 0; s < 2; ++s)
        #pragma unroll
        for (int j = 0; j < 8; ++j)
            bf[s][j] = f2bf(fmaxf(acc[2 * s + (j >> 2)][j & 3], 0.f));
}

// ---- persistent MLP: lean sequential body + split x double-buffer,
//      2 waves/SIMD (256-VGPR budget, no min-waves cap -> no spill) ----
__global__ __launch_bounds__(256) void k_mlp(
    const float* __restrict__ states, const float* __restrict__ next_states,
    const short8v* __restrict__ pk,
    const float* __restrict__ cb1, const float* __restrict__ ab1,
    const float* __restrict__ cb2, const float* __restrict__ ab2,
    const float* __restrict__ ab3,
    const float* __restrict__ cW3, const float* __restrict__ cb3,
    float* __restrict__ v_o, float* __restrict__ nv_o,
    short* __restrict__ logit_o)
{
    const int l = threadIdx.x & 63;
    const int g = l >> 4, q = l & 15;
    const int wid = blockIdx.x * 4 + (threadIdx.x >> 6);
    const float cb3v = cb3[0];
    int off[4];
    #pragma unroll
    for (int c = 0; c < 4; ++c) off[c] = ((c >> 1) << 5) + (g << 3) + ((c & 1) << 2);

    // prologue: tile `wid` raws
    float4 ra[8], rb[8];
    {
        const float* xs = states + ((long long)wid * 16 + q) * 128 + g * 8;
        const float* xn = next_states + ((long long)wid * 16 + q) * 128 + g * 8;
        #pragma unroll
        for (int s = 0; s < 4; ++s) {
            ra[2 * s]     = *reinterpret_cast<const float4*>(xs + s * 32);
            ra[2 * s + 1] = *reinterpret_cast<const float4*>(xs + s * 32 + 4);
            rb[2 * s]     = *reinterpret_cast<const float4*>(xn + s * 32);
            rb[2 * s + 1] = *reinterpret_cast<const float4*>(xn + s * 32 + 4);
        }
    }

    for (long long t = wid; t < NTILE; t += NWAVES) {
        const long long r0 = t * 16;
        const bool more = (t + NWAVES) < NTILE;

        // ========== states pass ==========
        short8v sa[4];
        #pragma unroll
        for (int s = 0; s < 4; ++s) sa[s] = cvt8(ra[2 * s], ra[2 * s + 1]);
        if (more) {   // prefetch next tile's states raws (full loop of flight)
            const float* xs = states + ((t + NWAVES) * 16 + q) * 128 + g * 8;
            #pragma unroll
            for (int s = 0; s < 4; ++s) {
                ra[2 * s]     = *reinterpret_cast<const float4*>(xs + s * 32);
                ra[2 * s + 1] = *reinterpret_cast<const float4*>(xs + s * 32 + 4);
            }
        }

        float4v acc[4];
        short8v bf[2];

        // critic L1
        #pragma unroll
        for (int c = 0; c < 4; ++c) {
            float4 b = *reinterpret_cast<const float4*>(cb1 + off[c]);
            acc[c] = (float4v){b.x, b.y, b.z, b.w};
        }
        #pragma unroll
        for (int s = 0; s < 4; ++s)
            #pragma unroll
            for (int c = 0; c < 4; ++c)
                acc[c] = __builtin_amdgcn_mfma_f32_16x16x32_bf16(
                    pk[(FC1 + s * 4 + c) * 64 + l], sa[s], acc[c], 0, 0, 0);
        mk_bfrag(acc, bf);

        // critic L2
        #pragma unroll
        for (int c = 0; c < 4; ++c) {
            float4 b = *reinterpret_cast<const float4*>(cb2 + off[c]);
            acc[c] = (float4v){b.x, b.y, b.z, b.w};
        }
        #pragma unroll
        for (int s = 0; s < 2; ++s)
            #pragma unroll
            for (int c = 0; c < 4; ++c)
                acc[c] = __builtin_amdgcn_mfma_f32_16x16x32_bf16(
                    pk[(FC2 + s * 4 + c) * 64 + l], bf[s], acc[c], 0, 0, 0);

        // critic head
        {
            float vp = 0.f;
            #pragma unroll
            for (int c = 0; c < 4; ++c) {
                float4 w3v = *reinterpret_cast<const float4*>(cW3 + off[c]);
                const float w4[4] = {w3v.x, w3v.y, w3v.z, w3v.w};
                #pragma unroll
                for (int u = 0; u < 4; ++u)
                    vp = fmaf(fmaxf(acc[c][u], 0.f), w4[u], vp);
            }
            vp += __shfl_xor(vp, 16); vp += __shfl_xor(vp, 32);
            if (g == 0) v_o[r0 + q] = vp + cb3v;
        }

        // actor L1 (reuses sa)
        #pragma unroll
        for (int c = 0; c < 4; ++c) {
            float4 b = *reinterpret_cast<const float4*>(ab1 + off[c]);
            acc[c] = (float4v){b.x, b.y, b.z, b.w};
        }
        #pragma unroll
        for (int s = 0; s < 4; ++s)
            #pragma unroll
            for (int c = 0; c < 4; ++c)
                acc[c] = __builtin_amdgcn_mfma_f32_16x16x32_bf16(
                    pk[(FA1 + s * 4 + c) * 64 + l], sa[s], acc[c], 0, 0, 0);
        mk_bfrag(acc, bf);

        // actor L2
        #pragma unroll
        for (int c = 0; c < 4; ++c) {
            float4 b = *reinterpret_cast<const float4*>(ab2 + off[c]);
            acc[c] = (float4v){b.x, b.y, b.z, b.w};
        }
        #pragma unroll
        for (int s = 0; s < 2; ++s)
            #pragma unroll
            for (int c = 0; c < 4; ++c)
                acc[c] = __builtin_amdgcn_mfma_f32_16x16x32_bf16(
                    pk[(FA2 + s * 4 + c) * 64 + l], bf[s], acc[c], 0, 0, 0);
        mk_bfrag(acc, bf);

        // actor L3 + logit store
        {
            float4 b3 = *reinterpret_cast<const float4*>(ab3 + g * 4);
            float4v a3 = (float4v){b3.x, b3.y, b3.z, b3.w};
            #pragma unroll
            for (int s = 0; s < 2; ++s)
                a3 = __builtin_amdgcn_mfma_f32_16x16x32_bf16(
                    pk[(FA3 + s) * 64 + l], bf[s], a3, 0, 0, 0);
            unsigned w0 = ((unsigned)(unsigned short)f2bf(a3[1]) << 16) |
                          (unsigned)(unsigned short)f2bf(a3[0]);
            unsigned w1 = ((unsigned)(unsigned short)f2bf(a3[3]) << 16) |
                          (unsigned)(unsigned short)f2bf(a3[2]);
            uint2 lw; lw.x = w0; lw.y = w1;
            *reinterpret_cast<uint2*>(logit_o + (r0 + q) * 16 + g * 4) = lw;
        }

        // ========== next_states pass ==========
        short8v na[4];
        #pragma unroll
        for (int s = 0; s < 4; ++s) na[s] = cvt8(rb[2 * s], rb[2 * s + 1]);
        if (more) {   // prefetch next tile's next_states raws
            const float* xn = next_states + ((t + NWAVES) * 16 + q) * 128 + g * 8;
            #pragma unroll
            for (int s = 0; s < 4; ++s) {
                rb[2 * s]     = *reinterpret_cast<const float4*>(xn + s * 32);
                rb[2 * s + 1] = *reinterpret_cast<const float4*>(xn + s * 32 + 4);
            }
        }

        #pragma unroll
        for (int c = 0; c < 4; ++c) {
            float4 b = *reinterpret_cast<const float4*>(cb1 + off[c]);
            acc[c] = (float4v){b.x, b.y, b.z, b.w};
        }
        #pragma unroll
        for (int s = 0; s < 4; ++s)
            #pragma unroll
            for (int c = 0; c < 4; ++c)
                acc[c] = __builtin_amdgcn_mfma_f32_16x16x32_bf16(
                    pk[(FC1 + s * 4 + c) * 64 + l], na[s], acc[c], 0, 0, 0);
        mk_bfrag(acc, bf);
        #pragma unroll
        for (int c = 0; c < 4; ++c) {
            float4 b = *reinterpret_cast<const float4*>(cb2 + off[c]);
            acc[c] = (float4v){b.x, b.y, b.z, b.w};
        }
        #pragma unroll
        for (int s = 0; s < 2; ++s)
            #pragma unroll
            for (int c = 0; c < 4; ++c)
                acc[c] = __builtin_amdgcn_mfma_f32_16x16x32_bf16(
                    pk[(FC2 + s * 4 + c) * 64 + l], bf[s], acc[c], 0, 0, 0);
        {
            float np = 0.f;
            #pragma unroll
            for (int c = 0; c < 4; ++c) {
                float4 w3v = *reinterpret_cast<const float4*>(cW3 + off[c]);
                const float w4[4] = {w3v.x, w3v.y, w3v.z, w3v.w};
                #pragma unroll
                for (int u = 0; u < 4; ++u)
                    np = fmaf(fmaxf(acc[c][u], 0.f), w4[u], np);
            }
            np += __shfl_xor(np, 16); np += __shfl_xor(np, 32);
            if (g == 0) nv_o[r0 + q] = np + cb3v;
        }
    }
}

// ---------------- GAE chunk: delta/coef on the fly ----------------
__device__ __forceinline__ void dc_elem(float v, float nv, float rw, float dn,
                                        float& d, float& c) {
    float nd = 1.f - dn;
    d = fmaf(0.99f * nd, nv, rw) - v;
    c = (0.99f * 0.95f) * nd;
}

__global__ __launch_bounds__(256) void k_gae_chunk(
    const float* __restrict__ v_i, const float* __restrict__ nv_i,
    const float* __restrict__ rewards, const float* __restrict__ dones,
    float* __restrict__ P, float* __restrict__ Q)
{
    const int c = blockIdx.x * 256 + threadIdx.x;
    const long long lo = (long long)c * CHUNKL;
    float p = 1.f, a = 0.f;
    if (lo < T_N) {
        const int n = (int)((T_N - lo < CHUNKL) ? (T_N - lo) : CHUNKL);
        for (int j = (n >> 2) - 1; j >= 0; --j) {
            float4 vv = *reinterpret_cast<const float4*>(&v_i[lo + 4 * j]);
            float4 nn = *reinterpret_cast<const float4*>(&nv_i[lo + 4 * j]);
            float4 rw = *reinterpret_cast<const float4*>(&rewards[lo + 4 * j]);
            float4 dn = *reinterpret_cast<const float4*>(&dones[lo + 4 * j]);
            float d0, c0, d1, c1, d2, c2, d3, c3;
            dc_elem(vv.x, nn.x, rw.x, dn.x, d0, c0);
            dc_elem(vv.y, nn.y, rw.y, dn.y, d1, c1);
            dc_elem(vv.z, nn.z, rw.z, dn.z, d2, c2);
            dc_elem(vv.w, nn.w, rw.w, dn.w, d3, c3);
            a = fmaf(c3, a, d3);
            a = fmaf(c2, a, d2);
            a = fmaf(c1, a, d1);
            a = fmaf(c0, a, d0);
            p *= c0 * c1 * c2 * c3;
        }
    }
    P[c] = p; Q[c] = a;
}

__global__ __launch_bounds__(1024) void k_gae_scan(
    const float* __restrict__ P, const float* __restrict__ Q,
    float* __restrict__ carry)
{
    __shared__ float sp[1024], sq[1024];
    const int t = threadIdx.x, b = t * 4;
    float p = P[b + 3], q = Q[b + 3];
    #pragma unroll
    for (int c = 2; c >= 0; --c) {
        float pc = P[b + c], qc = Q[b + c];
        q = fmaf(pc, q, qc);
        p = pc * p;
    }
    sp[t] = p; sq[t] = q;
    __syncthreads();
    for (int d = 1; d < 1024; d <<= 1) {
        float pp = sp[t], qq = sq[t];
        float p2 = 1.f, q2 = 0.f;
        const bool has = (t + d) < 1024;
        if (has) { p2 = sp[t + d]; q2 = sq[t + d]; }
        __syncthreads();
        if (has) { sp[t] = pp * p2; sq[t] = fmaf(pp, q2, qq); }
        __syncthreads();
    }
    float x = (t + 1 < 1024) ? sq[t + 1] : 0.f;
    #pragma unroll
    for (int c = 3; c >= 0; --c) {
        carry[b + c] = x;
        x = fmaf(P[b + c], x, Q[b + c]);
    }
}

__global__ __launch_bounds__(256) void k_gae_apply(
    const float* __restrict__ v_i, const float* __restrict__ nv_i,
    const float* __restrict__ rewards, const float* __restrict__ dones,
    const float* __restrict__ carry, float* __restrict__ adv,
    float* __restrict__ part)
{
    const int c = blockIdx.x * 256 + threadIdx.x;
    const long long lo = (long long)c * CHUNKL;
    float s = 0.f, s2 = 0.f;
    if (lo < T_N) {
        const int n = (int)((T_N - lo < CHUNKL) ? (T_N - lo) : CHUNKL);
        float a = carry[c];
        for (int j = (n >> 2) - 1; j >= 0; --j) {
            float4 vv = *reinterpret_cast<const float4*>(&v_i[lo + 4 * j]);
            float4 nn = *reinterpret_cast<const float4*>(&nv_i[lo + 4 * j]);
            float4 rw = *reinterpret_cast<const float4*>(&rewards[lo + 4 * j]);
            float4 dn = *reinterpret_cast<const float4*>(&dones[lo + 4 * j]);
            float d0, c0, d1, c1, d2, c2, d3, c3;
            dc_elem(vv.x, nn.x, rw.x, dn.x, d0, c0);
            dc_elem(vv.y, nn.y, rw.y, dn.y, d1, c1);
            dc_elem(vv.z, nn.z, rw.z, dn.z, d2, c2);
            dc_elem(vv.w, nn.w, rw.w, dn.w, d3, c3);
            float a3 = fmaf(c3, a, d3);
            float a2v = fmaf(c2, a3, d2);
            float a1 = fmaf(c1, a2v, d1);
            float a0 = fmaf(c0, a1, d0);
            float4 o; o.x = a0; o.y = a1; o.z = a2v; o.w = a3;
            *reinterpret_cast<float4*>(&adv[lo + 4 * j]) = o;
            a = a0;
            s += a0 + a1 + a2v + a3;
            s2 += a0 * a0 + a1 * a1 + a2v * a2v + a3 * a3;
        }
    }
    #pragma unroll
    for (int o = 32; o > 0; o >>= 1) { s += __shfl_down(s, o); s2 += __shfl_down(s2, o); }
    __shared__ float l0[4], l1[4];
    const int wv = threadIdx.x >> 6, ln = threadIdx.x & 63;
    if (ln == 0) { l0[wv] = s; l1[wv] = s2; }
    __syncthreads();
    if (threadIdx.x == 0) {
        part[blockIdx.x * 2]     = l0[0] + l0[1] + l0[2] + l0[3];
        part[blockIdx.x * 2 + 1] = l1[0] + l1[1] + l1[2] + l1[3];
    }
}

__global__ __launch_bounds__(256) void k_actor(
    const float* __restrict__ adv, const short* __restrict__ logits,
    const float* __restrict__ old_logp, const int* __restrict__ actions,
    const float* __restrict__ part, float* __restrict__ part4)
{
    __shared__ float st[2];
    if (threadIdx.x == 0) {
        float S = 0.f, S2 = 0.f;
        #pragma unroll
        for (int i = 0; i < 16; ++i) { S += part[2 * i]; S2 += part[2 * i + 1]; }
        const float Tf = (float)T_N;
        float mean = S / Tf;
        float var = (S2 - S * S / Tf) / (Tf - 1.f);
        st[0] = mean;
        st[1] = 1.f / (sqrtf(fmaxf(var, 0.f)) + 1e-8f);
    }
    __syncthreads();
    const float mean = st[0], isd = st[1];
    float sm = 0.f, sent = 0.f;
    for (long long i = (long long)blockIdx.x * 256 + threadIdx.x; i < T_N;
         i += (long long)gridDim.x * 256) {
        const short8v* lp = reinterpret_cast<const short8v*>(logits) + i * 2;
        short8v lo0 = lp[0], lo1 = lp[1];
        float lg[16];
        #pragma unroll
        for (int j = 0; j < 8; ++j) { lg[j] = bf2f(lo0[j]); lg[8 + j] = bf2f(lo1[j]); }
        float m = lg[0];
        #pragma unroll
        for (int a = 1; a < 16; ++a) m = fmaxf(m, lg[a]);
        float se = 0.f, tt = 0.f;
        #pragma unroll
        for (int a = 0; a < 16; ++a) {
            float e = __expf(lg[a] - m);
            se += e;
            tt = fmaf(e, lg[a], tt);
        }
        float ls = __logf(se);
        float ent = m + ls - tt / se;
        const int act = actions[i];
        float lsel = lg[0];
        #pragma unroll
        for (int a = 1; a < 16; ++a) lsel = (a == act) ? lg[a] : lsel;
        float logp = lsel - m - ls;
        float rt = __expf(logp - old_logp[i]);
        float an = (adv[i] - mean) * isd;
        sm += fminf(rt * an, fminf(fmaxf(rt, 0.8f), 1.2f) * an);
        sent += ent;
    }
    #pragma unroll
    for (int o = 32; o > 0; o >>= 1) { sm += __shfl_down(sm, o); sent += __shfl_down(sent, o); }
    __shared__ float l0[4], l1[4];
    const int wv = threadIdx.x >> 6, ln = threadIdx.x & 63;
    if (ln == 0) { l0[wv] = sm; l1[wv] = sent; }
    __syncthreads();
    if (threadIdx.x == 0) {
        part4[blockIdx.x * 2]     = l0[0] + l0[1] + l0[2] + l0[3];
        part4[blockIdx.x * 2 + 1] = l1[0] + l1[1] + l1[2] + l1[3];
    }
}

__global__ __launch_bounds__(1024) void k_final(
    const float* __restrict__ part4, const float* __restrict__ part,
    float* __restrict__ out)
{
    const int t = threadIdx.x;
    float sm = part4[t * 2], se = part4[t * 2 + 1];
    #pragma unroll
    for (int o = 32; o > 0; o >>= 1) { sm += __shfl_down(sm, o); se += __shfl_down(se, o); }
    __shared__ float l0[16], l1[16];
    const int wv = t >> 6, ln = t & 63;
    if (ln == 0) { l0[wv] = sm; l1[wv] = se; }
    __syncthreads();
    if (t == 0) {
        float SM = 0.f, SE = 0.f;
        #pragma unroll
        for (int i = 0; i < 16; ++i) { SM += l0[i]; SE += l1[i]; }
        float S2 = 0.f;
        #pragma unroll
        for (int i = 0; i < 16; ++i) S2 += part[2 * i + 1];
        const float Tf = (float)T_N;
        float actor_loss = -SM / Tf;
        float ent_loss = SE / Tf;
        float critic_loss = S2 / Tf;
        float total = actor_loss + 0.5f * critic_loss - 0.01f * ent_loss;
        out[0] = total; out[1] = actor_loss; out[2] = critic_loss; out[3] = ent_loss;
    }
}

extern "C" void kernel_launch(void* const* d_in, const int* in_sizes, int n_in,
                              void* d_out, int out_size, void* d_ws, size_t ws_size,
                              hipStream_t stream) {
    (void)in_sizes; (void)n_in; (void)out_size; (void)ws_size;
    const float* states      = (const float*)d_in[0];
    const float* next_states = (const float*)d_in[1];
    const float* rewards     = (const float*)d_in[2];
    const float* dones       = (const float*)d_in[3];
    const int*   actions     = (const int*)d_in[4];
    const float* old_logp    = (const float*)d_in[5];
    const float* aW1 = (const float*)d_in[6];  const float* ab1 = (const float*)d_in[7];
    const float* aW2 = (const float*)d_in[8];  const float* ab2 = (const float*)d_in[9];
    const float* aW3 = (const float*)d_in[10]; const float* ab3 = (const float*)d_in[11];
    const float* cW1 = (const float*)d_in[12]; const float* cb1 = (const float*)d_in[13];
    const float* cW2 = (const float*)d_in[14]; const float* cb2 = (const float*)d_in[15];
    const float* cW3 = (const float*)d_in[16]; const float* cb3 = (const float*)d_in[17];
    float* out = (float*)d_out;

    short* logits = (short*)d_ws;                           // 16 MB
    float* fbase = (float*)(logits + (size_t)T_N * 16);
    float* v_ws  = fbase;
    float* nv_ws = fbase + (size_t)T_N;
    float* adv   = fbase + 2 * (size_t)T_N;
    float* P     = fbase + 3 * (size_t)T_N;
    float* Q     = P + NCHUNK;
    float* carry = Q + NCHUNK;
    float* part  = carry + NCHUNK;
    float* part4 = part + 32;
    short8v* packed = (short8v*)(part4 + 2048);

    k_pack<<<NFRAG, 64, 0, stream>>>(cW1, aW1, cW2, aW2, aW3, packed);
    k_mlp<<<NBLK, 256, 0, stream>>>(
        states, next_states, packed,
        cb1, ab1, cb2, ab2, ab3, cW3, cb3, v_ws, nv_ws, logits);
    k_gae_chunk<<<NCHUNK / 256, 256, 0, stream>>>(v_ws, nv_ws, rewards, dones, P, Q);
    k_gae_scan<<<1, 1024, 0, stream>>>(P, Q, carry);
    k_gae_apply<<<NCHUNK / 256, 256, 0, stream>>>(v_ws, nv_ws, rewards, dones, carry, adv, part);
    k_actor<<<NPART, 256, 0, stream>>>(adv, logits, old_logp, actions, part, part4);
    k_final<<<1, 1024, 0, stream>>>(part4, part, out);
}

// Round 17
// 184.909 us; speedup vs baseline: 1.2396x; 1.0430x over previous
//
#include <hip/hip_runtime.h>
#include <hip/hip_bf16.h>

#define T_N 500000
#define NTILE 31250          // T_N / 16 rows per wave-tile (exact)
#define NBLK 1024            // 64-thread blocks: 1 wave each, 1 wave/SIMD
#define NWAVES NBLK
#define NCHUNK 4096
#define CHUNKL 128
#define NPART 1024

typedef __attribute__((ext_vector_type(8))) short short8v;
typedef __attribute__((ext_vector_type(4))) float float4v;

__device__ __forceinline__ short f2bf(float f) {
    __hip_bfloat16 b = __float2bfloat16(f);
    return *reinterpret_cast<short*>(&b);
}
__device__ __forceinline__ float bf2f(short s) {
    return __uint_as_float(((unsigned)(unsigned short)s) << 16);
}

__device__ __forceinline__ short8v cvt8(const float4 a, const float4 b) {
    short8v r;
    r[0] = f2bf(a.x); r[1] = f2bf(a.y); r[2] = f2bf(a.z); r[3] = f2bf(a.w);
    r[4] = f2bf(b.x); r[5] = f2bf(b.y); r[6] = f2bf(b.z); r[7] = f2bf(b.w);
    return r;
}

// W^T A-fragments (each = 64 lanes x 8 bf16 = 1KB)
#define FC1 0    // critic W1^T: 4 k-steps x 4 out-tiles
#define FA1 16   // actor  W1^T
#define FC2 32   // critic W2^T: 2 k-steps x 4 out-tiles
#define FA2 40   // actor  W2^T
#define FA3 48   // actor  W3^T: 2 k-steps (16 actions)
#define NFRAG 50

// output-feature permutation: C-row r of out-tile c holds feature feat(c,r),
// chosen so a lane's C-fragment IS the next layer's B-fragment.
__device__ __forceinline__ int featperm(int c, int r) {
    return ((c >> 1) << 5) + ((r >> 2) << 3) + ((c & 1) << 2) + (r & 3);
}

__global__ __launch_bounds__(64) void k_pack(
    const float* __restrict__ cW1, const float* __restrict__ aW1,
    const float* __restrict__ cW2, const float* __restrict__ aW2,
    const float* __restrict__ aW3, short8v* __restrict__ packed)
{
    const int f = blockIdx.x, l = threadIdx.x;
    const int g = l >> 4, r = l & 15;
    const float* W; int s, c, ncol; bool perm = true;
    if (f < FA1)      { W = cW1; s = f >> 2;         c = f & 3;         ncol = 64; }
    else if (f < FC2) { W = aW1; s = (f - FA1) >> 2; c = (f - FA1) & 3; ncol = 64; }
    else if (f < FA2) { W = cW2; s = (f - FC2) >> 2; c = (f - FC2) & 3; ncol = 64; }
    else if (f < FA3) { W = aW2; s = (f - FA2) >> 2; c = (f - FA2) & 3; ncol = 64; }
    else              { W = aW3; s = f - FA3;        c = 0;             ncol = 16; perm = false; }
    const int col = perm ? featperm(c, r) : r;
    short8v frag;
    #pragma unroll
    for (int j = 0; j < 8; ++j) {
        int k = s * 32 + g * 8 + j;        // W row = contraction index
        frag[j] = f2bf(W[k * ncol + col]);
    }
    packed[f * 64 + l] = frag;
}

// next layer's B-frag from accs: slot j of frag s = relu(acc[2s+(j>>2)][j&3])
__device__ __forceinline__ void mk_bfrag(const float4v* acc, short8v* bf) {
    #pragma unroll
    for (int s = 0; s < 2; ++s)
        #pragma unroll
        for (int j = 0; j < 8; ++j)
            bf[s][j] = f2bf(fmaxf(acc[2 * s + (j >> 2)][j & 3], 0.f));
}

// ---- persistent MLP: 1 wave/block, min-waves=1 -> full 512-VGPR budget.
// wf[50] weight frags register-targeted; lean sequential passes;
// split x double-buffer (ra' after states-cvt, rb' after next-cvt).
__global__ __launch_bounds__(64, 1) void k_mlp(
    const float* __restrict__ states, const float* __restrict__ next_states,
    const short8v* __restrict__ pk,
    const float* __restrict__ cb1, const float* __restrict__ ab1,
    const float* __restrict__ cb2, const float* __restrict__ ab2,
    const float* __restrict__ ab3,
    const float* __restrict__ cW3, const float* __restrict__ cb3,
    float* __restrict__ v_o, float* __restrict__ nv_o,
    short* __restrict__ logit_o)
{
    const int l = threadIdx.x;
    const int g = l >> 4, q = l & 15;
    const int wid = blockIdx.x;
    const float cb3v = cb3[0];
    int off[4];
    #pragma unroll
    for (int c = 0; c < 4; ++c) off[c] = ((c >> 1) << 5) + (g << 3) + ((c & 1) << 2);

    // ---- ALL weight fragments -> registers, once ----
    short8v wf[NFRAG];
    #pragma unroll
    for (int f = 0; f < NFRAG; ++f) wf[f] = pk[f * 64 + l];

    // ---- bias / head constants hoisted ----
    float4 bc1v[4], bc2v[4], ba1v[4], ba2v[4], w3v[4];
    #pragma unroll
    for (int c = 0; c < 4; ++c) {
        bc1v[c] = *reinterpret_cast<const float4*>(cb1 + off[c]);
        bc2v[c] = *reinterpret_cast<const float4*>(cb2 + off[c]);
        ba1v[c] = *reinterpret_cast<const float4*>(ab1 + off[c]);
        ba2v[c] = *reinterpret_cast<const float4*>(ab2 + off[c]);
        w3v[c]  = *reinterpret_cast<const float4*>(cW3 + off[c]);
    }
    const float4 ab3v = *reinterpret_cast<const float4*>(ab3 + g * 4);

    // ---- prologue: tile 0 raws ----
    float4 ra[8], rb[8];
    {
        const float* xs = states + ((long long)wid * 16 + q) * 128 + g * 8;
        const float* xn = next_states + ((long long)wid * 16 + q) * 128 + g * 8;
        #pragma unroll
        for (int s = 0; s < 4; ++s) {
            ra[2 * s]     = *reinterpret_cast<const float4*>(xs + s * 32);
            ra[2 * s + 1] = *reinterpret_cast<const float4*>(xs + s * 32 + 4);
            rb[2 * s]     = *reinterpret_cast<const float4*>(xn + s * 32);
            rb[2 * s + 1] = *reinterpret_cast<const float4*>(xn + s * 32 + 4);
        }
    }

    for (long long t = wid; t < NTILE; t += NWAVES) {
        const long long r0 = t * 16;
        const bool more = (t + NWAVES) < NTILE;

        // ========== states pass ==========
        short8v sa[4];
        #pragma unroll
        for (int s = 0; s < 4; ++s) sa[s] = cvt8(ra[2 * s], ra[2 * s + 1]);
        // prefetch next tile's states raws (consumed next iteration)
        if (more) {
            const float* xs = states + ((t + NWAVES) * 16 + q) * 128 + g * 8;
            #pragma unroll
            for (int s = 0; s < 4; ++s) {
                ra[2 * s]     = *reinterpret_cast<const float4*>(xs + s * 32);
                ra[2 * s + 1] = *reinterpret_cast<const float4*>(xs + s * 32 + 4);
            }
        }

        float4v acc[4];
        short8v bf[2];

        // critic L1
        #pragma unroll
        for (int c = 0; c < 4; ++c)
            acc[c] = (float4v){bc1v[c].x, bc1v[c].y, bc1v[c].z, bc1v[c].w};
        #pragma unroll
        for (int s = 0; s < 4; ++s)
            #pragma unroll
            for (int c = 0; c < 4; ++c)
                acc[c] = __builtin_amdgcn_mfma_f32_16x16x32_bf16(wf[FC1 + s * 4 + c], sa[s], acc[c], 0, 0, 0);
        mk_bfrag(acc, bf);

        // critic L2
        #pragma unroll
        for (int c = 0; c < 4; ++c)
            acc[c] = (float4v){bc2v[c].x, bc2v[c].y, bc2v[c].z, bc2v[c].w};
        #pragma unroll
        for (int s = 0; s < 2; ++s)
            #pragma unroll
            for (int c = 0; c < 4; ++c)
                acc[c] = __builtin_amdgcn_mfma_f32_16x16x32_bf16(wf[FC2 + s * 4 + c], bf[s], acc[c], 0, 0, 0);

        // critic head
        {
            float vp = 0.f;
            #pragma unroll
            for (int c = 0; c < 4; ++c) {
                const float w4[4] = {w3v[c].x, w3v[c].y, w3v[c].z, w3v[c].w};
                #pragma unroll
                for (int u = 0; u < 4; ++u)
                    vp = fmaf(fmaxf(acc[c][u], 0.f), w4[u], vp);
            }
            vp += __shfl_xor(vp, 16); vp += __shfl_xor(vp, 32);
            if (g == 0) v_o[r0 + q] = vp + cb3v;
        }

        // actor L1
        #pragma unroll
        for (int c = 0; c < 4; ++c)
            acc[c] = (float4v){ba1v[c].x, ba1v[c].y, ba1v[c].z, ba1v[c].w};
        #pragma unroll
        for (int s = 0; s < 4; ++s)
            #pragma unroll
            for (int c = 0; c < 4; ++c)
                acc[c] = __builtin_amdgcn_mfma_f32_16x16x32_bf16(wf[FA1 + s * 4 + c], sa[s], acc[c], 0, 0, 0);
        mk_bfrag(acc, bf);

        // actor L2
        #pragma unroll
        for (int c = 0; c < 4; ++c)
            acc[c] = (float4v){ba2v[c].x, ba2v[c].y, ba2v[c].z, ba2v[c].w};
        #pragma unroll
        for (int s = 0; s < 2; ++s)
            #pragma unroll
            for (int c = 0; c < 4; ++c)
                acc[c] = __builtin_amdgcn_mfma_f32_16x16x32_bf16(wf[FA2 + s * 4 + c], bf[s], acc[c], 0, 0, 0);
        mk_bfrag(acc, bf);

        // actor L3 + logit store
        {
            float4v a3 = (float4v){ab3v.x, ab3v.y, ab3v.z, ab3v.w};
            #pragma unroll
            for (int s = 0; s < 2; ++s)
                a3 = __builtin_amdgcn_mfma_f32_16x16x32_bf16(wf[FA3 + s], bf[s], a3, 0, 0, 0);
            unsigned w0 = ((unsigned)(unsigned short)f2bf(a3[1]) << 16) |
                          (unsigned)(unsigned short)f2bf(a3[0]);
            unsigned w1 = ((unsigned)(unsigned short)f2bf(a3[3]) << 16) |
                          (unsigned)(unsigned short)f2bf(a3[2]);
            uint2 lw; lw.x = w0; lw.y = w1;
            *reinterpret_cast<uint2*>(logit_o + (r0 + q) * 16 + g * 4) = lw;
        }

        // ========== next_states pass ==========
        short8v na[4];
        #pragma unroll
        for (int s = 0; s < 4; ++s) na[s] = cvt8(rb[2 * s], rb[2 * s + 1]);
        // prefetch next tile's next_states raws (consumed next iteration)
        if (more) {
            const float* xn = next_states + ((t + NWAVES) * 16 + q) * 128 + g * 8;
            #pragma unroll
            for (int s = 0; s < 4; ++s) {
                rb[2 * s]     = *reinterpret_cast<const float4*>(xn + s * 32);
                rb[2 * s + 1] = *reinterpret_cast<const float4*>(xn + s * 32 + 4);
            }
        }

        #pragma unroll
        for (int c = 0; c < 4; ++c)
            acc[c] = (float4v){bc1v[c].x, bc1v[c].y, bc1v[c].z, bc1v[c].w};
        #pragma unroll
        for (int s = 0; s < 4; ++s)
            #pragma unroll
            for (int c = 0; c < 4; ++c)
                acc[c] = __builtin_amdgcn_mfma_f32_16x16x32_bf16(wf[FC1 + s * 4 + c], na[s], acc[c], 0, 0, 0);
        mk_bfrag(acc, bf);
        #pragma unroll
        for (int c = 0; c < 4; ++c)
            acc[c] = (float4v){bc2v[c].x, bc2v[c].y, bc2v[c].z, bc2v[c].w};
        #pragma unroll
        for (int s = 0; s < 2; ++s)
            #pragma unroll
            for (int c = 0; c < 4; ++c)
                acc[c] = __builtin_amdgcn_mfma_f32_16x16x32_bf16(wf[FC2 + s * 4 + c], bf[s], acc[c], 0, 0, 0);
        {
            float np = 0.f;
            #pragma unroll
            for (int c = 0; c < 4; ++c) {
                const float w4[4] = {w3v[c].x, w3v[c].y, w3v[c].z, w3v[c].w};
                #pragma unroll
                for (int u = 0; u < 4; ++u)
                    np = fmaf(fmaxf(acc[c][u], 0.f), w4[u], np);
            }
            np += __shfl_xor(np, 16); np += __shfl_xor(np, 32);
            if (g == 0) nv_o[r0 + q] = np + cb3v;
        }
    }
}

// ---------------- GAE chunk: delta/coef on the fly ----------------
__device__ __forceinline__ void dc_elem(float v, float nv, float rw, float dn,
                                        float& d, float& c) {
    float nd = 1.f - dn;
    d = fmaf(0.99f * nd, nv, rw) - v;
    c = (0.99f * 0.95f) * nd;
}

__global__ __launch_bounds__(256) void k_gae_chunk(
    const float* __restrict__ v_i, const float* __restrict__ nv_i,
    const float* __restrict__ rewards, const float* __restrict__ dones,
    float* __restrict__ P, float* __restrict__ Q)
{
    const int c = blockIdx.x * 256 + threadIdx.x;
    const long long lo = (long long)c * CHUNKL;
    float p = 1.f, a = 0.f;
    if (lo < T_N) {
        const int n = (int)((T_N - lo < CHUNKL) ? (T_N - lo) : CHUNKL);
        for (int j = (n >> 2) - 1; j >= 0; --j) {
            float4 vv = *reinterpret_cast<const float4*>(&v_i[lo + 4 * j]);
            float4 nn = *reinterpret_cast<const float4*>(&nv_i[lo + 4 * j]);
            float4 rw = *reinterpret_cast<const float4*>(&rewards[lo + 4 * j]);
            float4 dn = *reinterpret_cast<const float4*>(&dones[lo + 4 * j]);
            float d0, c0, d1, c1, d2, c2, d3, c3;
            dc_elem(vv.x, nn.x, rw.x, dn.x, d0, c0);
            dc_elem(vv.y, nn.y, rw.y, dn.y, d1, c1);
            dc_elem(vv.z, nn.z, rw.z, dn.z, d2, c2);
            dc_elem(vv.w, nn.w, rw.w, dn.w, d3, c3);
            a = fmaf(c3, a, d3);
            a = fmaf(c2, a, d2);
            a = fmaf(c1, a, d1);
            a = fmaf(c0, a, d0);
            p *= c0 * c1 * c2 * c3;
        }
    }
    P[c] = p; Q[c] = a;
}

__global__ __launch_bounds__(1024) void k_gae_scan(
    const float* __restrict__ P, const float* __restrict__ Q,
    float* __restrict__ carry)
{
    __shared__ float sp[1024], sq[1024];
    const int t = threadIdx.x, b = t * 4;
    float p = P[b + 3], q = Q[b + 3];
    #pragma unroll
    for (int c = 2; c >= 0; --c) {
        float pc = P[b + c], qc = Q[b + c];
        q = fmaf(pc, q, qc);
        p = pc * p;
    }
    sp[t] = p; sq[t] = q;
    __syncthreads();
    for (int d = 1; d < 1024; d <<= 1) {
        float pp = sp[t], qq = sq[t];
        float p2 = 1.f, q2 = 0.f;
        const bool has = (t + d) < 1024;
        if (has) { p2 = sp[t + d]; q2 = sq[t + d]; }
        __syncthreads();
        if (has) { sp[t] = pp * p2; sq[t] = fmaf(pp, q2, qq); }
        __syncthreads();
    }
    float x = (t + 1 < 1024) ? sq[t + 1] : 0.f;
    #pragma unroll
    for (int c = 3; c >= 0; --c) {
        carry[b + c] = x;
        x = fmaf(P[b + c], x, Q[b + c]);
    }
}

__global__ __launch_bounds__(256) void k_gae_apply(
    const float* __restrict__ v_i, const float* __restrict__ nv_i,
    const float* __restrict__ rewards, const float* __restrict__ dones,
    const float* __restrict__ carry, float* __restrict__ adv,
    float* __restrict__ part)
{
    const int c = blockIdx.x * 256 + threadIdx.x;
    const long long lo = (long long)c * CHUNKL;
    float s = 0.f, s2 = 0.f;
    if (lo < T_N) {
        const int n = (int)((T_N - lo < CHUNKL) ? (T_N - lo) : CHUNKL);
        float a = carry[c];
        for (int j = (n >> 2) - 1; j >= 0; --j) {
            float4 vv = *reinterpret_cast<const float4*>(&v_i[lo + 4 * j]);
            float4 nn = *reinterpret_cast<const float4*>(&nv_i[lo + 4 * j]);
            float4 rw = *reinterpret_cast<const float4*>(&rewards[lo + 4 * j]);
            float4 dn = *reinterpret_cast<const float4*>(&dones[lo + 4 * j]);
            float d0, c0, d1, c1, d2, c2, d3, c3;
            dc_elem(vv.x, nn.x, rw.x, dn.x, d0, c0);
            dc_elem(vv.y, nn.y, rw.y, dn.y, d1, c1);
            dc_elem(vv.z, nn.z, rw.z, dn.z, d2, c2);
            dc_elem(vv.w, nn.w, rw.w, dn.w, d3, c3);
            float a3 = fmaf(c3, a, d3);
            float a2v = fmaf(c2, a3, d2);
            float a1 = fmaf(c1, a2v, d1);
            float a0 = fmaf(c0, a1, d0);
            float4 o; o.x = a0; o.y = a1; o.z = a2v; o.w = a3;
            *reinterpret_cast<float4*>(&adv[lo + 4 * j]) = o;
            a = a0;
            s += a0 + a1 + a2v + a3;
            s2 += a0 * a0 + a1 * a1 + a2v * a2v + a3 * a3;
        }
    }
    #pragma unroll
    for (int o = 32; o > 0; o >>= 1) { s += __shfl_down(s, o); s2 += __shfl_down(s2, o); }
    __shared__ float l0[4], l1[4];
    const int wv = threadIdx.x >> 6, ln = threadIdx.x & 63;
    if (ln == 0) { l0[wv] = s; l1[wv] = s2; }
    __syncthreads();
    if (threadIdx.x == 0) {
        part[blockIdx.x * 2]     = l0[0] + l0[1] + l0[2] + l0[3];
        part[blockIdx.x * 2 + 1] = l1[0] + l1[1] + l1[2] + l1[3];
    }
}

__global__ __launch_bounds__(256) void k_actor(
    const float* __restrict__ adv, const short* __restrict__ logits,
    const float* __restrict__ old_logp, const int* __restrict__ actions,
    const float* __restrict__ part, float* __restrict__ part4)
{
    __shared__ float st[2];
    if (threadIdx.x == 0) {
        float S = 0.f, S2 = 0.f;
        #pragma unroll
        for (int i = 0; i < 16; ++i) { S += part[2 * i]; S2 += part[2 * i + 1]; }
        const float Tf = (float)T_N;
        float mean = S / Tf;
        float var = (S2 - S * S / Tf) / (Tf - 1.f);
        st[0] = mean;
        st[1] = 1.f / (sqrtf(fmaxf(var, 0.f)) + 1e-8f);
    }
    __syncthreads();
    const float mean = st[0], isd = st[1];
    float sm = 0.f, sent = 0.f;
    for (long long i = (long long)blockIdx.x * 256 + threadIdx.x; i < T_N;
         i += (long long)gridDim.x * 256) {
        const short8v* lp = reinterpret_cast<const short8v*>(logits) + i * 2;
        short8v lo0 = lp[0], lo1 = lp[1];
        float lg[16];
        #pragma unroll
        for (int j = 0; j < 8; ++j) { lg[j] = bf2f(lo0[j]); lg[8 + j] = bf2f(lo1[j]); }
        float m = lg[0];
        #pragma unroll
        for (int a = 1; a < 16; ++a) m = fmaxf(m, lg[a]);
        float se = 0.f, tt = 0.f;
        #pragma unroll
        for (int a = 0; a < 16; ++a) {
            float e = __expf(lg[a] - m);
            se += e;
            tt = fmaf(e, lg[a], tt);
        }
        float ls = __logf(se);
        float ent = m + ls - tt / se;
        const int act = actions[i];
        float lsel = lg[0];
        #pragma unroll
        for (int a = 1; a < 16; ++a) lsel = (a == act) ? lg[a] : lsel;
        float logp = lsel - m - ls;
        float rt = __expf(logp - old_logp[i]);
        float an = (adv[i] - mean) * isd;
        sm += fminf(rt * an, fminf(fmaxf(rt, 0.8f), 1.2f) * an);
        sent += ent;
    }
    #pragma unroll
    for (int o = 32; o > 0; o >>= 1) { sm += __shfl_down(sm, o); sent += __shfl_down(sent, o); }
    __shared__ float l0[4], l1[4];
    const int wv = threadIdx.x >> 6, ln = threadIdx.x & 63;
    if (ln == 0) { l0[wv] = sm; l1[wv] = sent; }
    __syncthreads();
    if (threadIdx.x == 0) {
        part4[blockIdx.x * 2]     = l0[0] + l0[1] + l0[2] + l0[3];
        part4[blockIdx.x * 2 + 1] = l1[0] + l1[1] + l1[2] + l1[3];
    }
}

__global__ __launch_bounds__(1024) void k_final(
    const float* __restrict__ part4, const float* __restrict__ part,
    float* __restrict__ out)
{
    const int t = threadIdx.x;
    float sm = part4[t * 2], se = part4[t * 2 + 1];
    #pragma unroll
    for (int o = 32; o > 0; o >>= 1) { sm += __shfl_down(sm, o); se += __shfl_down(se, o); }
    __shared__ float l0[16], l1[16];
    const int wv = t >> 6, ln = t & 63;
    if (ln == 0) { l0[wv] = sm; l1[wv] = se; }
    __syncthreads();
    if (t == 0) {
        float SM = 0.f, SE = 0.f;
        #pragma unroll
        for (int i = 0; i < 16; ++i) { SM += l0[i]; SE += l1[i]; }
        float S2 = 0.f;
        #pragma unroll
        for (int i = 0; i < 16; ++i) S2 += part[2 * i + 1];
        const float Tf = (float)T_N;
        float actor_loss = -SM / Tf;
        float ent_loss = SE / Tf;
        float critic_loss = S2 / Tf;
        float total = actor_loss + 0.5f * critic_loss - 0.01f * ent_loss;
        out[0] = total; out[1] = actor_loss; out[2] = critic_loss; out[3] = ent_loss;
    }
}

extern "C" void kernel_launch(void* const* d_in, const int* in_sizes, int n_in,
                              void* d_out, int out_size, void* d_ws, size_t ws_size,
                              hipStream_t stream) {
    (void)in_sizes; (void)n_in; (void)out_size; (void)ws_size;
    const float* states      = (const float*)d_in[0];
    const float* next_states = (const float*)d_in[1];
    const float* rewards     = (const float*)d_in[2];
    const float* dones       = (const float*)d_in[3];
    const int*   actions     = (const int*)d_in[4];
    const float* old_logp    = (const float*)d_in[5];
    const float* aW1 = (const float*)d_in[6];  const float* ab1 = (const float*)d_in[7];
    const float* aW2 = (const float*)d_in[8];  const float* ab2 = (const float*)d_in[9];
    const float* aW3 = (const float*)d_in[10]; const float* ab3 = (const float*)d_in[11];
    const float* cW1 = (const float*)d_in[12]; const float* cb1 = (const float*)d_in[13];
    const float* cW2 = (const float*)d_in[14]; const float* cb2 = (const float*)d_in[15];
    const float* cW3 = (const float*)d_in[16]; const float* cb3 = (const float*)d_in[17];
    float* out = (float*)d_out;

    short* logits = (short*)d_ws;                           // 16 MB
    float* fbase = (float*)(logits + (size_t)T_N * 16);
    float* v_ws  = fbase;
    float* nv_ws = fbase + (size_t)T_N;
    float* adv   = fbase + 2 * (size_t)T_N;
    float* P     = fbase + 3 * (size_t)T_N;
    float* Q     = P + NCHUNK;
    float* carry = Q + NCHUNK;
    float* part  = carry + NCHUNK;
    float* part4 = part + 32;
    short8v* packed = (short8v*)(part4 + 2048);

    k_pack<<<NFRAG, 64, 0, stream>>>(cW1, aW1, cW2, aW2, aW3, packed);
    k_mlp<<<NBLK, 64, 0, stream>>>(
        states, next_states, packed,
        cb1, ab1, cb2, ab2, ab3, cW3, cb3, v_ws, nv_ws, logits);
    k_gae_chunk<<<NCHUNK / 256, 256, 0, stream>>>(v_ws, nv_ws, rewards, dones, P, Q);
    k_gae_scan<<<1, 1024, 0, stream>>>(P, Q, carry);
    k_gae_apply<<<NCHUNK / 256, 256, 0, stream>>>(v_ws, nv_ws, rewards, dones, carry, adv, part);
    k_actor<<<NPART, 256, 0, stream>>>(adv, logits, old_logp, actions, part, part4);
    k_final<<<1, 1024, 0, stream>>>(part4, part, out);
}